// Round 1
// baseline (2484.735 us; speedup 1.0000x reference)
//
#include <hip/hip_runtime.h>

#define N_ATOMS 100000
#define N_EDGES 300000
#define ATOM_DIM 32
#define BOND_DIM 16
#define STEPS 4

// One edge per lane. All W_bond / b_bond accesses are wave-uniform -> scalar loads.
// h_nbr (32 floats) held in VGPRs with static indexing only.
__global__ __launch_bounds__(256) void msg_kernel(
    const float* __restrict__ h,      // [N_ATOMS, 32]
    const float* __restrict__ bond,   // [N_EDGES, 16]
    const int*   __restrict__ pair,   // [N_EDGES, 2]  (dst, nbr)
    const float* __restrict__ Wb,     // [16, 1024]
    const float* __restrict__ bb,     // [1024]
    float*       __restrict__ agg)    // [N_ATOMS, 32], pre-zeroed
{
    int e = blockIdx.x * 256 + threadIdx.x;
    if (e >= N_EDGES) return;

    int dst = pair[2 * e + 0];
    int nbr = pair[2 * e + 1];

    float hv[ATOM_DIM];
#pragma unroll
    for (int j4 = 0; j4 < 8; ++j4) {
        float4 t = *reinterpret_cast<const float4*>(h + (size_t)nbr * ATOM_DIM + 4 * j4);
        hv[4 * j4 + 0] = t.x; hv[4 * j4 + 1] = t.y;
        hv[4 * j4 + 2] = t.z; hv[4 * j4 + 3] = t.w;
    }

    float c[BOND_DIM];
#pragma unroll
    for (int k4 = 0; k4 < 4; ++k4) {
        float4 t = *reinterpret_cast<const float4*>(bond + (size_t)e * BOND_DIM + 4 * k4);
        c[4 * k4 + 0] = t.x; c[4 * k4 + 1] = t.y;
        c[4 * k4 + 2] = t.z; c[4 * k4 + 3] = t.w;
    }

#pragma unroll 1
    for (int i = 0; i < ATOM_DIM; ++i) {
        // bias row contribution: dot(b_bond[i*32 : i*32+32], h_nbr)
        float acc = 0.f;
#pragma unroll
        for (int j = 0; j < 32; ++j)
            acc += bb[i * 32 + j] * hv[j];

#pragma unroll
        for (int k = 0; k < BOND_DIM; ++k) {
            float d = 0.f;
#pragma unroll
            for (int j = 0; j < 32; ++j)
                d += Wb[k * 1024 + i * 32 + j] * hv[j];
            acc += c[k] * d;
        }
        atomicAdd(&agg[(size_t)dst * ATOM_DIM + i], acc);
    }
}

// One atom per lane. GRU cell: r,z from sigmoid, n from tanh.
__global__ __launch_bounds__(256) void gru_kernel(
    const float* __restrict__ agg,    // [N_ATOMS, 32]  (x input)
    const float* __restrict__ hprev,  // [N_ATOMS, 32]
    const float* __restrict__ Wih,    // [96, 32]
    const float* __restrict__ Whh,    // [96, 32]
    const float* __restrict__ bih,    // [96]
    const float* __restrict__ bhh,    // [96]
    float*       __restrict__ hout)   // [N_ATOMS, 32]
{
    int a = blockIdx.x * 256 + threadIdx.x;
    if (a >= N_ATOMS) return;

    float x[ATOM_DIM], hv[ATOM_DIM];
#pragma unroll
    for (int j4 = 0; j4 < 8; ++j4) {
        float4 t = *reinterpret_cast<const float4*>(agg + (size_t)a * ATOM_DIM + 4 * j4);
        x[4 * j4 + 0] = t.x; x[4 * j4 + 1] = t.y;
        x[4 * j4 + 2] = t.z; x[4 * j4 + 3] = t.w;
        float4 u = *reinterpret_cast<const float4*>(hprev + (size_t)a * ATOM_DIM + 4 * j4);
        hv[4 * j4 + 0] = u.x; hv[4 * j4 + 1] = u.y;
        hv[4 * j4 + 2] = u.z; hv[4 * j4 + 3] = u.w;
    }

#pragma unroll 1
    for (int i = 0; i < ATOM_DIM; ++i) {
        float ir = bih[i], iz = bih[32 + i], inn = bih[64 + i];
        float hr = bhh[i], hz = bhh[32 + i], hn = bhh[64 + i];
#pragma unroll
        for (int j = 0; j < 32; ++j) {
            ir  += Wih[(i      ) * 32 + j] * x[j];
            iz  += Wih[(32 + i) * 32 + j] * x[j];
            inn += Wih[(64 + i) * 32 + j] * x[j];
            hr  += Whh[(i      ) * 32 + j] * hv[j];
            hz  += Whh[(32 + i) * 32 + j] * hv[j];
            hn  += Whh[(64 + i) * 32 + j] * hv[j];
        }
        float r = 1.f / (1.f + __expf(-(ir + hr)));
        float z = 1.f / (1.f + __expf(-(iz + hz)));
        float n = tanhf(inn + r * hn);
        // reload h[a,i] from L1 to avoid dynamic register-array indexing
        float hi = hprev[(size_t)a * ATOM_DIM + i];
        hout[(size_t)a * ATOM_DIM + i] = (1.f - z) * n + z * hi;
    }
}

extern "C" void kernel_launch(void* const* d_in, const int* in_sizes, int n_in,
                              void* d_out, int out_size, void* d_ws, size_t ws_size,
                              hipStream_t stream)
{
    const float* atom  = (const float*)d_in[0];
    const float* bond  = (const float*)d_in[1];
    const int*   pair  = (const int*)  d_in[2];
    const float* Wb    = (const float*)d_in[3];
    const float* bb    = (const float*)d_in[4];
    const float* W_ih  = (const float*)d_in[5];
    const float* W_hh  = (const float*)d_in[6];
    const float* b_ih  = (const float*)d_in[7];
    const float* b_hh  = (const float*)d_in[8];
    float* out = (float*)d_out;

    const size_t HB = (size_t)N_ATOMS * ATOM_DIM * sizeof(float);
    float* agg = (float*)d_ws;
    float* h0  = (float*)((char*)d_ws + HB);
    float* h1  = (float*)((char*)d_ws + 2 * HB);
    float* hbufs[2] = { h0, h1 };

    const int msg_blocks = (N_EDGES + 255) / 256;
    const int gru_blocks = (N_ATOMS + 255) / 256;

    const float* hcur = atom;
    for (int s = 0; s < STEPS; ++s) {
        hipMemsetAsync(agg, 0, HB, stream);
        msg_kernel<<<msg_blocks, 256, 0, stream>>>(hcur, bond, pair, Wb, bb, agg);
        float* hnext = (s == STEPS - 1) ? out : hbufs[s & 1];
        gru_kernel<<<gru_blocks, 256, 0, stream>>>(agg, hcur, W_ih, W_hh, b_ih, b_hh, hnext);
        hcur = hnext;
    }
}